// Round 5
// baseline (1245.523 us; speedup 1.0000x reference)
//
#include <hip/hip_runtime.h>
#include <cstdint>

// LlamaSmoothquantMLP on MI355X (gfx950).
//
// Round 5 = round 4 design (infra failure, no counters), hardened rewrite.
// Diagnosis behind it: in all LDS-staged variants, per wave-round LDS-read
// time (12 x ds_read_b128 x 12cyc = 144) == MFMA time (16 x 9.1 = 146) and
// LDS is CU-serial across 8 waves -> the 40-42% MfmaUtil wall. Fix: B
// (weights, consumed by exactly ONE wave in the 1Mx4N decomposition) loads
// global->VGPR directly, prefetched one BK=128 round ahead, double register
// bank, NO barrier coupling. Only A (shared by 4 waves) stays in LDS:
// triple-buffered, staged 2 rounds ahead (global_load_lds), published by one
// counted WAIT_VM + raw s_barrier per round (pattern proven in rounds 2-3).
// A uses the zero-conflict 8-slot pair-XOR layout (SQ_LDS_BANK_CONFLICT=0),
// as two 64-byte regions per BK=128 row.
//
// GEMMs: A [M,K] row-major, B [N,K] row-major. MFMA v_mfma_i32_32x32x32_i8.
// C/D layout m74/m101 (harness-verified in prior rounds).

typedef int v4i  __attribute__((ext_vector_type(4)));
typedef int v16i __attribute__((ext_vector_type(16)));

typedef const void __attribute__((address_space(1)))* gas_ptr;
typedef void __attribute__((address_space(3)))* las_ptr;

static constexpr int M_TOT = 4096;   // B*S
static constexpr int HDIM  = 4096;
static constexpr int IDIM  = 11008;

#define MFMA_I8(a, b, c) __builtin_amdgcn_mfma_i32_32x32x32_i8((a), (b), (c), 0, 0, 0)
#define BAR()        asm volatile("s_barrier" ::: "memory")
#define WAIT_VM(N)   asm volatile("s_waitcnt vmcnt(" #N ")" ::: "memory")
#define SETPRIO(P)   __builtin_amdgcn_s_setprio(P)

__device__ __forceinline__ void gload16(const int8_t* g, int8_t* l) {
  __builtin_amdgcn_global_load_lds((gas_ptr)g, (las_ptr)l, 16, 0, 0);
}

// ---------------- A-tile LDS geometry -------------------------------------
// 128 rows x 128 bytes as two 8 KiB regions (cols 0-63, 64-127), each with
// the 8-slot pair-XOR swizzle (measured SQ_LDS_BANK_CONFLICT = 0):
//   chunk (row, c) c=0..3 at byte  pair*128 + slot*16,
//   pair = row>>1, slot = ((c<<1)|(row&1)) ^ (pair&7).
// Staging writes LDS linearly (global_load_lds dest = base + lane*16); the
// global source is pre-inverse-swizzled via relmap64.
__device__ __forceinline__ v4i fragA(const int8_t* buf, int row, int cg) {
  const int pair = row >> 1;
  const int c    = cg & 3;
  const int slot = ((c << 1) | (row & 1)) ^ (pair & 7);
  return *(const v4i*)(buf + (cg >> 2) * 8192 + pair * 128 + slot * 16);
}

__device__ __forceinline__ void relmap64(int rel, int& row, int& col) {
  const int pair = rel >> 3;
  const int sl = (rel & 7) ^ (pair & 7);
  row = 2 * pair + (sl & 1);
  col = (sl >> 1) * 16;
}

__device__ __forceinline__ int inc3(int b) { return b == 2 ? 0 : b + 1; }

// ---------------- pack int32 -> int8, all four tensors in one dispatch ------
__device__ __forceinline__ void pack16(const int* __restrict__ src,
                                       int8_t* __restrict__ dst, int t) {
  const int4* s = (const int4*)(src) + t * 4;
  int4 v0 = s[0], v1 = s[1], v2 = s[2], v3 = s[3];
  int p0 = (v0.x & 0xff) | ((v0.y & 0xff) << 8) | ((v0.z & 0xff) << 16) | (v0.w << 24);
  int p1 = (v1.x & 0xff) | ((v1.y & 0xff) << 8) | ((v1.z & 0xff) << 16) | (v1.w << 24);
  int p2 = (v2.x & 0xff) | ((v2.y & 0xff) << 8) | ((v2.z & 0xff) << 16) | (v2.w << 24);
  int p3 = (v3.x & 0xff) | ((v3.y & 0xff) << 8) | ((v3.z & 0xff) << 16) | (v3.w << 24);
  ((int4*)dst)[t] = make_int4(p0, p1, p2, p3);
}

static constexpr int CX = (M_TOT * HDIM) / 16;            // 1,048,576
static constexpr int CW = (IDIM * HDIM) / 16;             // 2,818,048
static constexpr int CTOT = CX + 3 * CW;                  // 9,502,720

__global__ __launch_bounds__(256) void k_pack_all(
    const int* __restrict__ X32, const int* __restrict__ Wg32,
    const int* __restrict__ Wu32, const int* __restrict__ Wd32,
    int8_t* __restrict__ Xp, int8_t* __restrict__ Wgp,
    int8_t* __restrict__ Wup, int8_t* __restrict__ Wdp) {
  int t = blockIdx.x * blockDim.x + threadIdx.x;
  if (t >= CTOT) return;
  if (t < CX)               { pack16(X32,  Xp,  t); return; }
  t -= CX;
  if (t < CW)               { pack16(Wg32, Wgp, t); return; }
  t -= CW;
  if (t < CW)               { pack16(Wu32, Wup, t); return; }
  t -= CW;
  pack16(Wd32, Wdp, t);
}

// ---------------- shared helpers for the GEMM kernels ----------------------
// Stage one 128-row x 128B A-tile (16 KiB) into LDS buffer `base`.
__device__ __forceinline__ void stage_a(const int8_t* Ab, size_t ldk, int rr,
                                        size_t o0, size_t o1, int l0, int l1,
                                        int8_t* base) {
  const int8_t* g = Ab + (size_t)rr * 128;
  gload16(g + o0,      base + l0);
  gload16(g + o1,      base + l1);
  gload16(g + 64 + o0, base + 8192 + l0);
  gload16(g + 64 + o1, base + 8192 + l1);
  (void)ldk;
}

// Load one lane-row's 128 K-bytes (4 x 16B at 32B stride, half-offset folded
// into the base pointer) into a register bank.
__device__ __forceinline__ void loadB_row(const int8_t* p, v4i (&b)[4]) {
#pragma unroll
  for (int i = 0; i < 4; ++i) b[i] = *(const v4i*)(p + i * 32);
}

// ---------------- gate+up fused GEMM ----------------
// Block 128M x 128N, 256 thr (4 waves, 1Mx4N), wave tile 128M x 32N.
// A: LDS, 16 KiB/round, triple-buffered (48 KiB), staged 2 rounds ahead.
// G,U: direct global->VGPR, one round ahead, 2 register banks.
__device__ __forceinline__ void gu_compute(const int8_t* buf, int ln31, int half,
                                           const v4i (&bg)[4], const v4i (&bu)[4],
                                           v16i (&accG)[4], v16i (&accU)[4]) {
  SETPRIO(1);
#pragma unroll
  for (int ks = 0; ks < 4; ++ks) {
    const int cg = 2 * ks + half;
    v4i a0 = fragA(buf, ln31,      cg);
    v4i a1 = fragA(buf, ln31 + 32, cg);
    v4i a2 = fragA(buf, ln31 + 64, cg);
    v4i a3 = fragA(buf, ln31 + 96, cg);
    accG[0] = MFMA_I8(a0, bg[ks], accG[0]);
    accU[0] = MFMA_I8(a0, bu[ks], accU[0]);
    accG[1] = MFMA_I8(a1, bg[ks], accG[1]);
    accU[1] = MFMA_I8(a1, bu[ks], accU[1]);
    accG[2] = MFMA_I8(a2, bg[ks], accG[2]);
    accU[2] = MFMA_I8(a2, bu[ks], accU[2]);
    accG[3] = MFMA_I8(a3, bg[ks], accG[3]);
    accU[3] = MFMA_I8(a3, bu[ks], accU[3]);
  }
  SETPRIO(0);
}

__global__ __launch_bounds__(256, 2) void k_gateup(
    const int8_t* __restrict__ X,
    const int8_t* __restrict__ Wg,
    const int8_t* __restrict__ Wu,
    const float* __restrict__ gate_a, const float* __restrict__ gate_b,
    const float* __restrict__ up_a,   const float* __restrict__ up_b,
    const float* __restrict__ down_scale,
    int8_t* __restrict__ Q) {
  __shared__ __align__(16) int8_t lds8[3 * 16384];   // 48 KiB

  const int tid  = threadIdx.x;
  const int lane = tid & 63;
  const int wn   = tid >> 6;        // 0..3 : N quarter (32 cols)
  const int half = lane >> 5;
  const int ln31 = lane & 31;

  const int m0 = blockIdx.x * 128;
  const int n0 = blockIdx.y * 128;

  const int8_t* Ab = X + (size_t)m0 * HDIM;

  // A staging: per region 512 chunks; this thread stages chunks tid, tid+256.
  int r0, c0, r1, c1;
  relmap64(tid,       r0, c0);
  relmap64(tid + 256, r1, c1);
  const size_t oA0 = (size_t)r0 * HDIM + c0;
  const size_t oA1 = (size_t)r1 * HDIM + c1;
  const int l0 = tid * 16;
  const int l1 = (tid + 256) * 16;

  // B direct-load row pointers (this lane's output column; half-k folded in)
  const int n_lane = n0 + wn * 32 + ln31;
  const int8_t* Gp = Wg + (size_t)n_lane * HDIM + half * 16;
  const int8_t* Up = Wu + (size_t)n_lane * HDIM + half * 16;

  v16i accG[4], accU[4];
#pragma unroll
  for (int i = 0; i < 4; ++i)
#pragma unroll
    for (int e = 0; e < 16; ++e) { accG[i][e] = 0; accU[i][e] = 0; }

  v4i bG0[4], bU0[4], bG1[4], bU1[4];

  const int NT = HDIM / 128;  // 32 rounds (even)

  // prologue: stage A(0),A(1); load B(0) into bank0; publish A(0).
  stage_a(Ab, HDIM, 0, oA0, oA1, l0, l1, lds8);
  stage_a(Ab, HDIM, 1, oA0, oA1, l0, l1, lds8 + 16384);
  loadB_row(Gp, bG0);
  loadB_row(Up, bU0);
  WAIT_VM(12);   // retire A(0); A(1)+B(0) stay in flight
  BAR();

  int bcur = 0;  // LDS buffer holding the round being computed
  for (int r = 0; r < NT; r += 2) {
    // ---- round r: consume bank0; load bank1; stage A(r+2) ----
    {
      if (r + 1 < NT) {
        loadB_row(Gp + (size_t)(r + 1) * 128, bG1);
        loadB_row(Up + (size_t)(r + 1) * 128, bU1);
      }
      if (r + 2 < NT) {
        const int bst = inc3(inc3(bcur));
        stage_a(Ab, HDIM, r + 2, oA0, oA1, l0, l1, lds8 + bst * 16384);
      }
      gu_compute(lds8 + bcur * 16384, ln31, half, bG0, bU0, accG, accU);
      if (r + 1 < NT) {
        if (r + 2 < NT) { WAIT_VM(12); } else { WAIT_VM(8); }
        BAR();
      }
      bcur = inc3(bcur);
    }
    // ---- round r+1: consume bank1; load bank0; stage A(r+3) ----
    {
      if (r + 2 < NT) {
        loadB_row(Gp + (size_t)(r + 2) * 128, bG0);
        loadB_row(Up + (size_t)(r + 2) * 128, bU0);
      }
      if (r + 3 < NT) {
        const int bst = inc3(inc3(bcur));
        stage_a(Ab, HDIM, r + 3, oA0, oA1, l0, l1, lds8 + bst * 16384);
      }
      gu_compute(lds8 + bcur * 16384, ln31, half, bG1, bU1, accG, accU);
      if (r + 2 < NT) {
        if (r + 3 < NT) { WAIT_VM(12); } else { WAIT_VM(8); }
        BAR();
      }
      bcur = inc3(bcur);
    }
  }

  const float ga = gate_a[0];
  const float ua = up_a[0];
  const float inv_ds = 1.0f / down_scale[0];
  const int n = n0 + wn * 32 + ln31;
  const float gb = gate_b[n];
  const float ub = up_b[n];

#pragma unroll
  for (int tm = 0; tm < 4; ++tm) {
#pragma unroll
    for (int e = 0; e < 16; ++e) {
      // C/D layout (m74/m101): col=lane&31, row=(e&3)+8*(e>>2)+4*(lane>>5)
      const int row_l = (e & 3) + 8 * (e >> 2) + 4 * half;
      const int m = m0 + tm * 32 + row_l;
      const float g = (float)accG[tm][e] * ga + gb;
      const float u = (float)accU[tm][e] * ua + ub;
      const float sg = g / (1.0f + __expf(-g));
      const float inter = sg * u;
      float qf = rintf(inter * inv_ds);
      qf = fminf(127.0f, fmaxf(-128.0f, qf));
      Q[(size_t)m * IDIM + n] = (int8_t)qf;
    }
  }
}

// ---------------- down GEMM ----------------
// Block 128M x 256N, 256 thr (4 waves, 1Mx4N), wave tile 128M x 64N.
// A (Q): LDS triple-buffered; Wd: direct global->VGPR one round ahead
// (2 weight rows per lane: n_row0 and n_row0+32).
// Grid 32x16 = 512 blocks = exactly 2/CU.
__device__ __forceinline__ void dn_compute(const int8_t* buf, int ln31, int half,
                                           const v4i (&b0)[4], const v4i (&b1)[4],
                                           v16i (&acc)[4][2]) {
  SETPRIO(1);
#pragma unroll
  for (int ks = 0; ks < 4; ++ks) {
    const int cg = 2 * ks + half;
    v4i a0 = fragA(buf, ln31,      cg);
    v4i a1 = fragA(buf, ln31 + 32, cg);
    v4i a2 = fragA(buf, ln31 + 64, cg);
    v4i a3 = fragA(buf, ln31 + 96, cg);
    acc[0][0] = MFMA_I8(a0, b0[ks], acc[0][0]);
    acc[0][1] = MFMA_I8(a0, b1[ks], acc[0][1]);
    acc[1][0] = MFMA_I8(a1, b0[ks], acc[1][0]);
    acc[1][1] = MFMA_I8(a1, b1[ks], acc[1][1]);
    acc[2][0] = MFMA_I8(a2, b0[ks], acc[2][0]);
    acc[2][1] = MFMA_I8(a2, b1[ks], acc[2][1]);
    acc[3][0] = MFMA_I8(a3, b0[ks], acc[3][0]);
    acc[3][1] = MFMA_I8(a3, b1[ks], acc[3][1]);
  }
  SETPRIO(0);
}

__global__ __launch_bounds__(256, 2) void k_down(
    const int8_t* __restrict__ Qm,
    const int8_t* __restrict__ Wd,
    const float* __restrict__ down_a, const float* __restrict__ down_b,
    float* __restrict__ Out) {
  __shared__ __align__(16) int8_t lds8[3 * 16384];   // 48 KiB

  const int tid  = threadIdx.x;
  const int lane = tid & 63;
  const int wn   = tid >> 6;        // 0..3 : N quarter (64 cols)
  const int half = lane >> 5;
  const int ln31 = lane & 31;

  const int m0 = blockIdx.x * 128;
  const int n0 = blockIdx.y * 256;

  const int8_t* Ab = Qm + (size_t)m0 * IDIM;

  int r0, c0, r1, c1;
  relmap64(tid,       r0, c0);
  relmap64(tid + 256, r1, c1);
  const size_t oA0 = (size_t)r0 * IDIM + c0;
  const size_t oA1 = (size_t)r1 * IDIM + c1;
  const int l0 = tid * 16;
  const int l1 = (tid + 256) * 16;

  const int n_row0 = n0 + wn * 64 + ln31;
  const int8_t* B0p = Wd + (size_t)n_row0 * IDIM + half * 16;
  const int8_t* B1p = B0p + (size_t)32 * IDIM;

  v16i acc[4][2];
#pragma unroll
  for (int i = 0; i < 4; ++i)
#pragma unroll
    for (int j = 0; j < 2; ++j)
#pragma unroll
      for (int e = 0; e < 16; ++e) acc[i][j][e] = 0;

  v4i bA0[4], bB0[4], bA1[4], bB1[4];   // banks: (b0row, b1row) x 2

  const int NT = IDIM / 128;  // 86 rounds (even)

  stage_a(Ab, IDIM, 0, oA0, oA1, l0, l1, lds8);
  stage_a(Ab, IDIM, 1, oA0, oA1, l0, l1, lds8 + 16384);
  loadB_row(B0p, bA0);
  loadB_row(B1p, bB0);
  WAIT_VM(12);
  BAR();

  int bcur = 0;
  for (int r = 0; r < NT; r += 2) {
    // ---- round r: consume bank0 ----
    {
      if (r + 1 < NT) {
        loadB_row(B0p + (size_t)(r + 1) * 128, bA1);
        loadB_row(B1p + (size_t)(r + 1) * 128, bB1);
      }
      if (r + 2 < NT) {
        const int bst = inc3(inc3(bcur));
        stage_a(Ab, IDIM, r + 2, oA0, oA1, l0, l1, lds8 + bst * 16384);
      }
      dn_compute(lds8 + bcur * 16384, ln31, half, bA0, bB0, acc);
      if (r + 1 < NT) {
        if (r + 2 < NT) { WAIT_VM(12); } else { WAIT_VM(8); }
        BAR();
      }
      bcur = inc3(bcur);
    }
    // ---- round r+1: consume bank1 ----
    {
      if (r + 2 < NT) {
        loadB_row(B0p + (size_t)(r + 2) * 128, bA0);
        loadB_row(B1p + (size_t)(r + 2) * 128, bB0);
      }
      if (r + 3 < NT) {
        const int bst = inc3(inc3(bcur));
        stage_a(Ab, IDIM, r + 3, oA0, oA1, l0, l1, lds8 + bst * 16384);
      }
      dn_compute(lds8 + bcur * 16384, ln31, half, bA1, bB1, acc);
      if (r + 2 < NT) {
        if (r + 3 < NT) { WAIT_VM(12); } else { WAIT_VM(8); }
        BAR();
      }
      bcur = inc3(bcur);
    }
  }

  const float da = down_a[0];
#pragma unroll
  for (int tn = 0; tn < 2; ++tn) {
    const int n = n0 + wn * 64 + tn * 32 + ln31;
    const float db = down_b[n];
#pragma unroll
    for (int tm = 0; tm < 4; ++tm) {
#pragma unroll
      for (int e = 0; e < 16; ++e) {
        const int row_l = (e & 3) + 8 * (e >> 2) + 4 * half;
        const int m = m0 + tm * 32 + row_l;
        Out[(size_t)m * HDIM + n] = (float)acc[tm][tn][e] * da + db;
      }
    }
  }
}

extern "C" void kernel_launch(void* const* d_in, const int* in_sizes, int n_in,
                              void* d_out, int out_size, void* d_ws, size_t ws_size,
                              hipStream_t stream) {
  const int* X32        = (const int*)d_in[0];
  const int* Wg32       = (const int*)d_in[1];
  const int* Wu32       = (const int*)d_in[2];
  const int* Wd32       = (const int*)d_in[3];
  const float* gate_a   = (const float*)d_in[4];
  const float* gate_b   = (const float*)d_in[5];
  const float* up_a     = (const float*)d_in[6];
  const float* up_b     = (const float*)d_in[7];
  const float* down_a   = (const float*)d_in[8];
  const float* down_b   = (const float*)d_in[9];
  const float* down_scale = (const float*)d_in[10];
  float* Out = (float*)d_out;

  const size_t nX = (size_t)M_TOT * HDIM;
  const size_t nW = (size_t)IDIM * HDIM;

  // Workspace: Q | Xp | Wgp | Wup | Wdp  (~197 MB)
  int8_t* Q   = (int8_t*)d_ws;
  int8_t* Xp  = Q   + nW;
  int8_t* Wgp = Xp  + nX;
  int8_t* Wup = Wgp + nW;
  int8_t* Wdp = Wup + nW;

  k_pack_all<<<(CTOT + 255) / 256, 256, 0, stream>>>(X32, Wg32, Wu32, Wd32,
                                                     Xp, Wgp, Wup, Wdp);

  k_gateup<<<dim3(M_TOT / 128, IDIM / 128), dim3(256), 0, stream>>>(
      Xp, Wgp, Wup, gate_a, gate_b, up_a, up_b, down_scale, Q);

  k_down<<<dim3(M_TOT / 128, HDIM / 256), dim3(256), 0, stream>>>(
      Q, Wdp, down_a, down_b, Out);
}

// Round 6
// 1040.850 us; speedup vs baseline: 1.1966x; 1.1966x over previous
//
#include <hip/hip_runtime.h>
#include <cstdint>

// LlamaSmoothquantMLP on MI355X (gfx950).
//
// Round 6: switch MFMA shape 32x32x32 -> 16x16x64 (K=64 per 16B fragment,
// 4 C-regs). This halves LDS reads per MFMA (0.75 -> 0.375 reads/MFMA at
// wave tile 128x64 / gateup's shared-A 128x32(G+U)), turning the balanced
// LDS-vs-MFMA pipes (the measured 40-42% MfmaUtil wall of rounds 1-3) into
// an MFMA-dominant budget. Structure = round-2 skeleton (fastest measured):
// BK=128 full-line staging via global_load_lds, double-buffered LDS, ONE
// covered vmcnt(0)+s_barrier per K-tile, setprio around MFMA clusters.
// New conflict-free swizzle for the 16-row fragment geometry:
//   chunk (row, c) c=0..7 at byte row*128 + ((c ^ (row&7))*16)
// -> a wave's frag read (16 rows x 4 c-groups) hits each bank-quad exactly
// 8/64 lanes = hardware minimum (conflict-free).
// B-direct-to-VGPR (round 5) is DEAD: B fragments are 32-row gathers.
//
// GEMMs: A [M,K] row-major, B [N,K] row-major. C/D layout for 16x16 (m89,
// dtype-independent): col = lane&15, row = (lane>>4)*4 + reg.

typedef int v4i  __attribute__((ext_vector_type(4)));

typedef const void __attribute__((address_space(1)))* gas_ptr;
typedef void __attribute__((address_space(3)))* las_ptr;

static constexpr int M_TOT = 4096;   // B*S
static constexpr int HDIM  = 4096;
static constexpr int IDIM  = 11008;

#define MFMA16(a, b, c) __builtin_amdgcn_mfma_i32_16x16x64_i8((a), (b), (c), 0, 0, 0)
#define BAR()        asm volatile("s_barrier" ::: "memory")
#define WAIT_VM0()   asm volatile("s_waitcnt vmcnt(0)" ::: "memory")
#define SETPRIO(P)   __builtin_amdgcn_s_setprio(P)

__device__ __forceinline__ void gload16(const int8_t* g, int8_t* l) {
  __builtin_amdgcn_global_load_lds((gas_ptr)g, (las_ptr)l, 16, 0, 0);
}

// ---------------- LDS tile geometry (rows x 128B, XOR-8 slot swizzle) ------
// Fragment read: lane l, fragment row-base R0, K-half kh:
//   row = R0 + (l&15), c = kh*4 + (l>>4), slot = c ^ (row&7).
// Staging inverse: chunk q -> r = q>>3, c = (q&7) ^ (r&7), gsrc r*ld + c*16,
// LDS dst = q*16 (linear, as global_load_lds requires).
__device__ __forceinline__ v4i fragR(const int8_t* region, int row, int cb) {
  const int slot = cb ^ (row & 7);
  return *(const v4i*)(region + row * 128 + slot * 16);
}

__device__ __forceinline__ size_t srcmap(int q, int ld) {
  const int r = q >> 3;
  const int c = (q & 7) ^ (r & 7);
  return (size_t)r * ld + c * 16;
}

// ---------------- pack int32 -> int8, all four tensors in one dispatch ------
__device__ __forceinline__ void pack16(const int* __restrict__ src,
                                       int8_t* __restrict__ dst, int t) {
  const int4* s = (const int4*)(src) + t * 4;
  int4 v0 = s[0], v1 = s[1], v2 = s[2], v3 = s[3];
  int p0 = (v0.x & 0xff) | ((v0.y & 0xff) << 8) | ((v0.z & 0xff) << 16) | (v0.w << 24);
  int p1 = (v1.x & 0xff) | ((v1.y & 0xff) << 8) | ((v1.z & 0xff) << 16) | (v1.w << 24);
  int p2 = (v2.x & 0xff) | ((v2.y & 0xff) << 8) | ((v2.z & 0xff) << 16) | (v2.w << 24);
  int p3 = (v3.x & 0xff) | ((v3.y & 0xff) << 8) | ((v3.z & 0xff) << 16) | (v3.w << 24);
  ((int4*)dst)[t] = make_int4(p0, p1, p2, p3);
}

static constexpr int CX = (M_TOT * HDIM) / 16;            // 1,048,576
static constexpr int CW = (IDIM * HDIM) / 16;             // 2,818,048
static constexpr int CTOT = CX + 3 * CW;                  // 9,502,720

__global__ __launch_bounds__(256) void k_pack_all(
    const int* __restrict__ X32, const int* __restrict__ Wg32,
    const int* __restrict__ Wu32, const int* __restrict__ Wd32,
    int8_t* __restrict__ Xp, int8_t* __restrict__ Wgp,
    int8_t* __restrict__ Wup, int8_t* __restrict__ Wdp) {
  int t = blockIdx.x * blockDim.x + threadIdx.x;
  if (t >= CTOT) return;
  if (t < CX)               { pack16(X32,  Xp,  t); return; }
  t -= CX;
  if (t < CW)               { pack16(Wg32, Wgp, t); return; }
  t -= CW;
  if (t < CW)               { pack16(Wu32, Wup, t); return; }
  t -= CW;
  pack16(Wd32, Wdp, t);
}

// ---------------- gate+up fused GEMM ----------------
// Block 256M x 128N (G and U both), 512 thr, 8 waves (2M x 4N),
// wave tile 128M x 32N for BOTH matrices (shared A reads).
// LDS/tile 64 KiB: A[0,32K) 256r, G[32K,48K) 128r, U[48K,64K) 128r. Dbuf=128K.
// Per K-tile per wave: 24 ds_read_b128, 64 MFMA(16x16x64). acc = 128 AGPR.
__global__ __launch_bounds__(512, 2) void k_gateup(
    const int8_t* __restrict__ X,
    const int8_t* __restrict__ Wg,
    const int8_t* __restrict__ Wu,
    const float* __restrict__ gate_a, const float* __restrict__ gate_b,
    const float* __restrict__ up_a,   const float* __restrict__ up_b,
    const float* __restrict__ down_scale,
    int8_t* __restrict__ Q) {
  __shared__ __align__(16) int8_t lds8[2 * 65536];

  const int tid  = threadIdx.x;
  const int lane = tid & 63;
  const int wave = tid >> 6;
  const int wm   = wave >> 2;       // 0..1 : M half (128 rows)
  const int wn   = wave & 3;        // 0..3 : N quarter (32 cols)
  const int r16  = lane & 15;
  const int quad = lane >> 4;       // 0..3

  const int m0 = blockIdx.x * 256;
  const int n0 = blockIdx.y * 128;

  const int8_t* Ab = X  + (size_t)m0 * HDIM;
  const int8_t* Gb = Wg + (size_t)n0 * HDIM;
  const int8_t* Ub = Wu + (size_t)n0 * HDIM;

  // staging source offsets (inverse-swizzled). A: 2048 chunks -> 4/thread;
  // G,U: 1024 chunks -> 2/thread each. Total 8 gloads/thread/tile.
  size_t oA[4], oW[2];
#pragma unroll
  for (int j = 0; j < 4; ++j) oA[j] = srcmap(tid + j * 512, HDIM);
#pragma unroll
  for (int j = 0; j < 2; ++j) oW[j] = srcmap(tid + j * 512, HDIM);

  v4i accG[8][2], accU[8][2];
#pragma unroll
  for (int i = 0; i < 8; ++i)
#pragma unroll
    for (int j = 0; j < 2; ++j)
#pragma unroll
      for (int e = 0; e < 4; ++e) { accG[i][j][e] = 0; accU[i][j][e] = 0; }

#define GU_STAGE(t_, sb)                                                \
  {                                                                     \
    const size_t ks = (size_t)(t_) * 128;                               \
    _Pragma("unroll")                                                   \
    for (int j = 0; j < 4; ++j)                                         \
      gload16(Ab + ks + oA[j], (sb) + (tid + j * 512) * 16);            \
    _Pragma("unroll")                                                   \
    for (int j = 0; j < 2; ++j) {                                       \
      gload16(Gb + ks + oW[j], (sb) + 32768 + (tid + j * 512) * 16);    \
      gload16(Ub + ks + oW[j], (sb) + 49152 + (tid + j * 512) * 16);    \
    }                                                                   \
  }

  const int NT = HDIM / 128;  // 32 K-tiles

  GU_STAGE(0, lds8)
  WAIT_VM0();
  BAR();

  for (int t = 0; t < NT; ++t) {
    const int8_t* bufA = lds8 + (t & 1) * 65536;
    const int8_t* bufG = bufA + 32768;
    const int8_t* bufU = bufA + 49152;

    if (t + 1 < NT) GU_STAGE(t + 1, lds8 + ((t + 1) & 1) * 65536)

    SETPRIO(1);
#pragma unroll
    for (int kh = 0; kh < 2; ++kh) {
      const int cb = kh * 4 + quad;
      v4i a_[8], g_[2], u_[2];
#pragma unroll
      for (int mi = 0; mi < 8; ++mi)
        a_[mi] = fragR(bufA, wm * 128 + mi * 16 + r16, cb);
#pragma unroll
      for (int ni = 0; ni < 2; ++ni) {
        g_[ni] = fragR(bufG, wn * 32 + ni * 16 + r16, cb);
        u_[ni] = fragR(bufU, wn * 32 + ni * 16 + r16, cb);
      }
#pragma unroll
      for (int mi = 0; mi < 8; ++mi)
#pragma unroll
        for (int ni = 0; ni < 2; ++ni) {
          accG[mi][ni] = MFMA16(a_[mi], g_[ni], accG[mi][ni]);
          accU[mi][ni] = MFMA16(a_[mi], u_[ni], accU[mi][ni]);
        }
    }
    SETPRIO(0);

    if (t + 1 < NT) {
      WAIT_VM0();   // staged loads flew for the whole compute phase
      BAR();
    }
  }
#undef GU_STAGE

  const float ga = gate_a[0];
  const float ua = up_a[0];
  const float inv_ds = 1.0f / down_scale[0];

#pragma unroll
  for (int ni = 0; ni < 2; ++ni) {
    const int n = n0 + wn * 32 + ni * 16 + r16;
    const float gb = gate_b[n];
    const float ub = up_b[n];
#pragma unroll
    for (int mi = 0; mi < 8; ++mi) {
      const int mbase = m0 + wm * 128 + mi * 16 + quad * 4;
#pragma unroll
      for (int e = 0; e < 4; ++e) {
        const int m = mbase + e;   // C/D: col=lane&15, row=(lane>>4)*4+e
        const float g = (float)accG[mi][ni][e] * ga + gb;
        const float u = (float)accU[mi][ni][e] * ua + ub;
        const float sg = g / (1.0f + __expf(-g));
        const float inter = sg * u;
        float qf = rintf(inter * inv_ds);
        qf = fminf(127.0f, fmaxf(-128.0f, qf));
        Q[(size_t)m * IDIM + n] = (int8_t)qf;
      }
    }
  }
}

// ---------------- down GEMM ----------------
// Block 256M x 256N, 512 thr, 8 waves (2M x 4N), wave tile 128M x 64N.
// LDS/tile 64 KiB: A[0,32K) 256r, B[32K,64K) 256r. Dbuf = 128 KiB.
// Grid 16x16 = 256 blocks = exactly 1/CU. acc = 128 AGPR.
__global__ __launch_bounds__(512, 2) void k_down(
    const int8_t* __restrict__ Qm,
    const int8_t* __restrict__ Wd,
    const float* __restrict__ down_a, const float* __restrict__ down_b,
    float* __restrict__ Out) {
  __shared__ __align__(16) int8_t lds8[2 * 65536];

  const int tid  = threadIdx.x;
  const int lane = tid & 63;
  const int wave = tid >> 6;
  const int wm   = wave >> 2;       // 0..1 : M half (128 rows)
  const int wn   = wave & 3;        // 0..3 : N quarter (64 cols)
  const int r16  = lane & 15;
  const int quad = lane >> 4;

  const int m0 = blockIdx.x * 256;
  const int n0 = blockIdx.y * 256;

  const int8_t* Ab = Qm + (size_t)m0 * IDIM;
  const int8_t* Bb = Wd + (size_t)n0 * IDIM;

  size_t oA[4], oB[4];
#pragma unroll
  for (int j = 0; j < 4; ++j) {
    oA[j] = srcmap(tid + j * 512, IDIM);
    oB[j] = oA[j];
  }

  v4i acc[8][4];
#pragma unroll
  for (int i = 0; i < 8; ++i)
#pragma unroll
    for (int j = 0; j < 4; ++j)
#pragma unroll
      for (int e = 0; e < 4; ++e) acc[i][j][e] = 0;

#define DN_STAGE(t_, sb)                                                \
  {                                                                     \
    const size_t ks = (size_t)(t_) * 128;                               \
    _Pragma("unroll")                                                   \
    for (int j = 0; j < 4; ++j) {                                       \
      gload16(Ab + ks + oA[j], (sb) + (tid + j * 512) * 16);            \
      gload16(Bb + ks + oB[j], (sb) + 32768 + (tid + j * 512) * 16);    \
    }                                                                   \
  }

  const int NT = IDIM / 128;  // 86 K-tiles

  DN_STAGE(0, lds8)
  WAIT_VM0();
  BAR();

  for (int t = 0; t < NT; ++t) {
    const int8_t* bufA = lds8 + (t & 1) * 65536;
    const int8_t* bufB = bufA + 32768;

    if (t + 1 < NT) DN_STAGE(t + 1, lds8 + ((t + 1) & 1) * 65536)

    SETPRIO(1);
#pragma unroll
    for (int kh = 0; kh < 2; ++kh) {
      const int cb = kh * 4 + quad;
      v4i a_[8], b_[4];
#pragma unroll
      for (int mi = 0; mi < 8; ++mi)
        a_[mi] = fragR(bufA, wm * 128 + mi * 16 + r16, cb);
#pragma unroll
      for (int ni = 0; ni < 4; ++ni)
        b_[ni] = fragR(bufB, wn * 64 + ni * 16 + r16, cb);
#pragma unroll
      for (int mi = 0; mi < 8; ++mi)
#pragma unroll
        for (int ni = 0; ni < 4; ++ni)
          acc[mi][ni] = MFMA16(a_[mi], b_[ni], acc[mi][ni]);
    }
    SETPRIO(0);

    if (t + 1 < NT) {
      WAIT_VM0();
      BAR();
    }
  }
#undef DN_STAGE

  const float da = down_a[0];
#pragma unroll
  for (int ni = 0; ni < 4; ++ni) {
    const int n = n0 + wn * 64 + ni * 16 + r16;
    const float db = down_b[n];
#pragma unroll
    for (int mi = 0; mi < 8; ++mi) {
      const int mbase = m0 + wm * 128 + mi * 16 + quad * 4;
#pragma unroll
      for (int e = 0; e < 4; ++e) {
        const int m = mbase + e;
        Out[(size_t)m * HDIM + n] = (float)acc[mi][ni][e] * da + db;
      }
    }
  }
}

extern "C" void kernel_launch(void* const* d_in, const int* in_sizes, int n_in,
                              void* d_out, int out_size, void* d_ws, size_t ws_size,
                              hipStream_t stream) {
  const int* X32        = (const int*)d_in[0];
  const int* Wg32       = (const int*)d_in[1];
  const int* Wu32       = (const int*)d_in[2];
  const int* Wd32       = (const int*)d_in[3];
  const float* gate_a   = (const float*)d_in[4];
  const float* gate_b   = (const float*)d_in[5];
  const float* up_a     = (const float*)d_in[6];
  const float* up_b     = (const float*)d_in[7];
  const float* down_a   = (const float*)d_in[8];
  const float* down_b   = (const float*)d_in[9];
  const float* down_scale = (const float*)d_in[10];
  float* Out = (float*)d_out;

  const size_t nX = (size_t)M_TOT * HDIM;
  const size_t nW = (size_t)IDIM * HDIM;

  // Workspace: Q | Xp | Wgp | Wup | Wdp  (~197 MB)
  int8_t* Q   = (int8_t*)d_ws;
  int8_t* Xp  = Q   + nW;
  int8_t* Wgp = Xp  + nX;
  int8_t* Wup = Wgp + nW;
  int8_t* Wdp = Wup + nW;

  k_pack_all<<<(CTOT + 255) / 256, 256, 0, stream>>>(X32, Wg32, Wu32, Wd32,
                                                     Xp, Wgp, Wup, Wdp);

  k_gateup<<<dim3(M_TOT / 256, IDIM / 128), dim3(512), 0, stream>>>(
      Xp, Wgp, Wup, gate_a, gate_b, up_a, up_b, down_scale, Q);

  k_down<<<dim3(M_TOT / 256, HDIM / 256), dim3(512), 0, stream>>>(
      Q, Wdp, down_a, down_b, Out);
}